// Round 7
// baseline (675.398 us; speedup 1.0000x reference)
//
#include <hip/hip_runtime.h>
#include <hip/hip_fp16.h>
#include <stdint.h>

#define HIDDEN 4096
#define FFN    14336
#define MDIM   512
#define G1     224   // FFN / 64
#define G2     64    // HIDDEN / 64
#define BK     64

typedef _Float16 f16x8 __attribute__((ext_vector_type(8)));
typedef float f32x4 __attribute__((ext_vector_type(4)));

#define SCHED0() __builtin_amdgcn_sched_barrier(0);
#define LGKM_BAR()                                            \
    asm volatile("s_waitcnt lgkmcnt(0)" ::: "memory");        \
    __builtin_amdgcn_s_barrier();                             \
    __builtin_amdgcn_sched_barrier(0);

// ---------------- prep kernels ----------------

__global__ void cvt_x_kernel(const float* __restrict__ x, ushort* __restrict__ xb) {
    int i = blockIdx.x * blockDim.x + threadIdx.x;   // one float4 per thread
    float4 v = ((const float4*)x)[i];
    __half2 a = __floats2half2_rn(v.x, v.y);
    __half2 b = __floats2half2_rn(v.z, v.w);
    ((uint2*)xb)[i] = make_uint2(__builtin_bit_cast(uint32_t, a),
                                 __builtin_bit_cast(uint32_t, b));
}

// out[2i] = {f16(s0), f16(s1)}, out[2i+1] = {f16(-z0*s0), f16(-z1*s1)}
__global__ void build_sz_kernel(const float* __restrict__ s, const float* __restrict__ z,
                                uint32_t* __restrict__ outp) {
    int i = blockIdx.x * blockDim.x + threadIdx.x;
    float s0 = s[2 * i], s1 = s[2 * i + 1];
    float z0 = z[2 * i], z1 = z[2 * i + 1];
    __half2 hs = __floats2half2_rn(s0, s1);
    __half2 hn = __floats2half2_rn(-z0 * s0, -z1 * s1);
    ((uint2*)outp)[i] = make_uint2(__builtin_bit_cast(uint32_t, hs),
                                   __builtin_bit_cast(uint32_t, hn));
}

// dequant 2 codes -> packed f16 pair: table-select via v_perm + v_pk_fma_f16
__device__ __forceinline__ uint32_t deq2(uint32_t w0, uint32_t w1, uint32_t sh,
                                         uint32_t spair, uint32_t npair) {
    uint32_t c0 = (w0 >> sh) & 3u;
    uint32_t c1 = (w1 >> sh) & 3u;
    uint32_t sel = 0x01000100u + c0 * 0x0202u + c1 * 0x02020000u;
    uint32_t codes = __builtin_amdgcn_perm(0x42004000u, 0x3C000000u, sel); // f16{0,1,2,3}
    __half2 r = __hfma2(__builtin_bit_cast(__half2, codes),
                        __builtin_bit_cast(__half2, spair),
                        __builtin_bit_cast(__half2, npair));
    return __builtin_bit_cast(uint32_t, r);
}

// ---------------- GEMM A: gate/up fused + SwiGLU -> h (f16) ----------------
// BM=256, BN=32, BK=64, 4 waves stacked in M (wave tile 64x32).
// A: DIRECT global->reg (xb L2-resident; no LDS staging). B: dbuf LDS dequant.
// One lgkm barrier per K-step. VGPR budget <=128 -> 4 blocks/CU.

__global__ __launch_bounds__(256, 4)
void gemm_gateup(const ushort* __restrict__ xb, const uint32_t* __restrict__ qw1,
                 const uint32_t* __restrict__ sz1, const uint32_t* __restrict__ qw3,
                 const uint32_t* __restrict__ sz3, ushort* __restrict__ hbuf) {
    __shared__ ushort sB1[2][32 * 64];    // 8 KB
    __shared__ ushort sB2[2][32 * 64];    // 8 KB
    __shared__ ushort sE[256 * 32];       // 16 KB epilogue staging

    const int tid = threadIdx.x;
    // XCD swizzle: 896 = 8 x 112; mt fast (mt pairs share B inputs in L2)
    const int idx = ((blockIdx.x & 7) * 112) + (blockIdx.x >> 3);
    const int mt = idx & 1, nt = idx >> 1;
    const int m0 = mt * 256, n0 = nt * 32;

    const int lane = tid & 63, w = tid >> 6;
    const int wm = w * 64;
    const int frow = lane & 15, fk = (lane >> 4) * 8;
    const int sw = (frow & 7) << 3;       // B read-side XOR swizzle

    // A direct-load offsets (32-bit; saddr + voffset form)
    uint32_t aoff[4];
#pragma unroll
    for (int i = 0; i < 4; ++i)
        aoff[i] = (uint32_t)(m0 + wm + i * 16 + frow) * HIDDEN + fk;

    // B staging: threads 0-127 gate, 128-255 up; 2 rows x 8 k each
    const int bi = tid & 127;
    const int rp = bi >> 3;               // 0..15 row-pair
    const int kc = (bi & 7) * 8;
    const int row0 = rp * 2;
    const int g0 = (n0 + row0) % G1;      // even, <=222; g0+1 no wrap
    const uint32_t* qp = (tid < 128 ? qw1 : qw3) + (size_t)(n0 / 4 + (rp >> 1)) * HIDDEN + kc;
    const uint32_t* zp = (tid < 128 ? sz1 : sz3) + (size_t)g0 * HIDDEN + kc;
    ushort (*sB)[32 * 64] = (tid < 128) ? sB1 : sB2;
    const uint32_t sh0 = 6u - 4u * (uint32_t)(rp & 1);

    f32x4 accG[4][2], accU[4][2];
#pragma unroll
    for (int i = 0; i < 4; ++i)
#pragma unroll
        for (int j = 0; j < 2; ++j) {
            accG[i][j] = (f32x4){0.f, 0.f, 0.f, 0.f};
            accU[i][j] = (f32x4){0.f, 0.f, 0.f, 0.f};
        }

    uint4 pw0, pw1;   // qw prefetch, 1 step deep (8 VGPR)

#define GU_LDQW(k0q)                                                           \
    pw0 = *(const uint4*)(qp + (k0q));                                         \
    pw1 = *(const uint4*)(qp + (k0q) + 4);

// sz loaded inline (L2-hot); compiler inserts the waits
#define GU_DEQ(wbuf, k0z)                                                      \
    { uint4 pz0 = *(const uint4*)(zp + (k0z));                                 \
      uint4 pz1 = *(const uint4*)(zp + (k0z) + 4);                             \
      uint4 pz2 = *(const uint4*)(zp + HIDDEN + (k0z));                        \
      uint4 pz3 = *(const uint4*)(zp + HIDDEN + (k0z) + 4);                    \
      const uint32_t wv[8] = {pw0.x, pw0.y, pw0.z, pw0.w,                      \
                              pw1.x, pw1.y, pw1.z, pw1.w};                     \
      {   const uint32_t sp[4] = {pz0.x, pz0.z, pz1.x, pz1.z};                 \
          const uint32_t np[4] = {pz0.y, pz0.w, pz1.y, pz1.w};                 \
          uint32_t o[4];                                                       \
          _Pragma("unroll")                                                    \
          for (int j = 0; j < 4; ++j)                                          \
              o[j] = deq2(wv[2*j], wv[2*j+1], sh0, sp[j], np[j]);              \
          *(uint4*)&sB[wbuf][row0 * 64 + (kc ^ ((row0 & 7) << 3))] =           \
              make_uint4(o[0], o[1], o[2], o[3]);                              \
      }                                                                        \
      {   const uint32_t sp[4] = {pz2.x, pz2.z, pz3.x, pz3.z};                 \
          const uint32_t np[4] = {pz2.y, pz2.w, pz3.y, pz3.w};                 \
          uint32_t o[4];                                                       \
          _Pragma("unroll")                                                    \
          for (int j = 0; j < 4; ++j)                                          \
              o[j] = deq2(wv[2*j], wv[2*j+1], sh0 - 2u, sp[j], np[j]);         \
          const int row1 = row0 + 1;                                           \
          *(uint4*)&sB[wbuf][row1 * 64 + (kc ^ ((row1 & 7) << 3))] =           \
              make_uint4(o[0], o[1], o[2], o[3]);                              \
      } }

// load this step's A fragments direct to regs, then MFMA against sB[rbuf]
#define GU_COMP(rbuf, k0a)                                                     \
    { f16x8 af0[4], af1[4];                                                    \
      _Pragma("unroll")                                                        \
      for (int i = 0; i < 4; ++i) {                                            \
          af0[i] = *(const f16x8*)&xb[aoff[i] + (k0a)];                        \
          af1[i] = *(const f16x8*)&xb[aoff[i] + (k0a) + 32];                   \
      }                                                                        \
      _Pragma("unroll")                                                        \
      for (int kk = 0; kk < 2; ++kk) {                                         \
          const int col = ((kk * 32) + fk) ^ sw;                               \
          f16x8 bg[2], bu[2];                                                  \
          bg[0] = *(const f16x8*)&sB1[rbuf][frow * 64 + col];                  \
          bg[1] = *(const f16x8*)&sB1[rbuf][(16 + frow) * 64 + col];           \
          bu[0] = *(const f16x8*)&sB2[rbuf][frow * 64 + col];                  \
          bu[1] = *(const f16x8*)&sB2[rbuf][(16 + frow) * 64 + col];           \
          _Pragma("unroll")                                                    \
          for (int mi = 0; mi < 4; ++mi) {                                     \
              f16x8 a = kk ? af1[mi] : af0[mi];                                \
              _Pragma("unroll")                                                \
              for (int ni = 0; ni < 2; ++ni) {                                 \
                  accG[mi][ni] = __builtin_amdgcn_mfma_f32_16x16x32_f16(a, bg[ni], accG[mi][ni], 0, 0, 0); \
                  accU[mi][ni] = __builtin_amdgcn_mfma_f32_16x16x32_f16(a, bu[ni], accU[mi][ni], 0, 0, 0); \
              } } } }

// step t: DEQ(t+1 -> wbuf) || LDQW(t+2) || COMP(t, rbuf); one barrier
#define GU_STEP(tcur, WBUF, RBUF, DOPF)                                        \
    { GU_DEQ(WBUF, ((tcur) + 1) * BK)                                          \
      if (DOPF) { GU_LDQW(((tcur) + 2) * BK) }                                 \
      GU_COMP(RBUF, (tcur) * BK)                                               \
      LGKM_BAR() }

    // prologue: dequant tile 0 into buf0; qw(tile1) in flight
    GU_LDQW(0)
    GU_DEQ(0, 0)
    GU_LDQW(BK)
    LGKM_BAR()

    for (int t = 0; t < 62; t += 2) {
        GU_STEP(t,     1, 0, 1)
        GU_STEP(t + 1, 0, 1, 1)
    }
    GU_STEP(62, 1, 0, 0)
    GU_COMP(1, 63 * BK)   // tile 63

    // ---- epilogue: silu(gate)*up -> LDS -> coalesced f16 stores ----
    const int rb = (lane >> 4) * 4, cb = lane & 15;
#pragma unroll
    for (int mi = 0; mi < 4; ++mi)
#pragma unroll
        for (int ni = 0; ni < 2; ++ni) {
            f32x4 g = accG[mi][ni], u = accU[mi][ni];
            const int row = wm + mi * 16 + rb;
            const int colx = ni * 16 + cb;
#pragma unroll
            for (int r = 0; r < 4; ++r) {
                float gv = g[r];
                float hv = __fdividef(gv, 1.0f + __expf(-gv)) * u[r];
                __half hh = __float2half(hv);
                sE[(row + r) * 32 + colx] = __builtin_bit_cast(ushort, hh);
            }
        }
    __syncthreads();
    {
        ushort* dst = hbuf + (size_t)(m0 + tid) * FFN + n0;
        const ushort* src = sE + tid * 32;
#pragma unroll
        for (int i = 0; i < 4; ++i)
            *(uint4*)(dst + 8 * i) = *(const uint4*)(src + 8 * i);
    }
#undef GU_LDQW
#undef GU_DEQ
#undef GU_COMP
#undef GU_STEP
}

// ---------------- GEMM B: out_partial = h @ w2^T (split-K = 2) ----------------
// BM=128, BN=32, BK=64, 4 waves stacked in M (wave tile 32x32); grid 1024.
// A direct from hbuf (L3-resident); B dbuf LDS dequant.

__global__ __launch_bounds__(256, 4)
void gemm_down(const ushort* __restrict__ hb, const uint32_t* __restrict__ qw2,
               const uint32_t* __restrict__ sz2, float* __restrict__ part) {
    __shared__ ushort sBd[2][32 * 64];    // 8 KB

    const int tid = threadIdx.x;
    // 1024 = 8 x 128 XCD swizzle
    const int idx = ((blockIdx.x & 7) * 128) + (blockIdx.x >> 3);
    const int mt = idx & 3, nt = (idx >> 2) & 127, sk = idx >> 9;
    const int m0 = mt * 128, n0 = nt * 32;
    const int kbeg = sk * (FFN / 2);

    const int lane = tid & 63, w = tid >> 6;
    const int wm = w * 32;
    const int frow = lane & 15, fk = (lane >> 4) * 8;
    const int sw = (frow & 7) << 3;

    uint32_t aoff[2];
#pragma unroll
    for (int i = 0; i < 2; ++i)
        aoff[i] = (uint32_t)(m0 + wm + i * 16 + frow) * FFN + kbeg + fk;

    // B staging: 1 row x 8 k per thread (32 rows x 8 chunks = 256)
    const int r = tid >> 3;               // 0..31
    const int kc = (tid & 7) * 8;
    const int g = ((nt & 1) * 32) + r;    // (n0 + r) % 64
    const uint32_t* qp = qw2 + (size_t)(n0 / 4 + (r >> 2)) * FFN + kbeg + kc;
    const uint32_t* zp = sz2 + (size_t)g * FFN + kbeg + kc;
    const uint32_t sh = 6u - 2u * (uint32_t)(r & 3);

    f32x4 acc[2][2];
#pragma unroll
    for (int i = 0; i < 2; ++i)
#pragma unroll
        for (int j = 0; j < 2; ++j) acc[i][j] = (f32x4){0.f, 0.f, 0.f, 0.f};

    uint4 pw0, pw1;

#define GD_LDQW(k0q)                                                           \
    pw0 = *(const uint4*)(qp + (k0q));                                         \
    pw1 = *(const uint4*)(qp + (k0q) + 4);

#define GD_DEQ(wbuf, k0z)                                                      \
    { uint4 pz0 = *(const uint4*)(zp + (k0z));                                 \
      uint4 pz1 = *(const uint4*)(zp + (k0z) + 4);                             \
      const uint32_t wv[8] = {pw0.x, pw0.y, pw0.z, pw0.w,                      \
                              pw1.x, pw1.y, pw1.z, pw1.w};                     \
      const uint32_t sp[4] = {pz0.x, pz0.z, pz1.x, pz1.z};                     \
      const uint32_t np[4] = {pz0.y, pz0.w, pz1.y, pz1.w};                     \
      uint32_t o[4];                                                           \
      _Pragma("unroll")                                                        \
      for (int j = 0; j < 4; ++j)                                              \
          o[j] = deq2(wv[2*j], wv[2*j+1], sh, sp[j], np[j]);                   \
      *(uint4*)&sBd[wbuf][r * 64 + (kc ^ ((r & 7) << 3))] =                    \
          make_uint4(o[0], o[1], o[2], o[3]); }

#define GD_COMP(rbuf, k0a)                                                     \
    { f16x8 af0[2], af1[2];                                                    \
      _Pragma("unroll")                                                        \
      for (int i = 0; i < 2; ++i) {                                            \
          af0[i] = *(const f16x8*)&hb[aoff[i] + (k0a)];                        \
          af1[i] = *(const f16x8*)&hb[aoff[i] + (k0a) + 32];                   \
      }                                                                        \
      _Pragma("unroll")                                                        \
      for (int kk = 0; kk < 2; ++kk) {                                         \
          const int col = ((kk * 32) + fk) ^ sw;                               \
          f16x8 bf[2];                                                         \
          bf[0] = *(const f16x8*)&sBd[rbuf][frow * 64 + col];                  \
          bf[1] = *(const f16x8*)&sBd[rbuf][(16 + frow) * 64 + col];           \
          _Pragma("unroll")                                                    \
          for (int mi = 0; mi < 2; ++mi) {                                     \
              f16x8 a = kk ? af1[mi] : af0[mi];                                \
              _Pragma("unroll")                                                \
              for (int ni = 0; ni < 2; ++ni)                                   \
                  acc[mi][ni] = __builtin_amdgcn_mfma_f32_16x16x32_f16(a, bf[ni], acc[mi][ni], 0, 0, 0); \
          } } }

#define GD_STEP(tcur, WBUF, RBUF, DOPF)                                        \
    { GD_DEQ(WBUF, ((tcur) + 1) * BK)                                          \
      if (DOPF) { GD_LDQW(((tcur) + 2) * BK) }                                 \
      GD_COMP(RBUF, (tcur) * BK)                                               \
      LGKM_BAR() }

    GD_LDQW(0)
    GD_DEQ(0, 0)
    GD_LDQW(BK)
    LGKM_BAR()

    for (int t = 0; t < 110; t += 2) {
        GD_STEP(t,     1, 0, 1)
        GD_STEP(t + 1, 0, 1, 1)
    }
    GD_STEP(110, 1, 0, 0)
    GD_COMP(1, 111 * BK)   // tile 111

    float* pp = part + (size_t)sk * MDIM * HIDDEN;
    const int rb = (lane >> 4) * 4, cb = lane & 15;
#pragma unroll
    for (int mi = 0; mi < 2; ++mi)
#pragma unroll
        for (int ni = 0; ni < 2; ++ni) {
            f32x4 a = acc[mi][ni];
            const int mm = m0 + wm + mi * 16 + rb;
            const int nn = n0 + ni * 16 + cb;
#pragma unroll
            for (int rr = 0; rr < 4; ++rr) pp[(size_t)(mm + rr) * HIDDEN + nn] = a[rr];
        }
#undef GD_LDQW
#undef GD_DEQ
#undef GD_COMP
#undef GD_STEP
}

// ---------------- reduce split-K partials ----------------

__global__ void reduce_out(const float* __restrict__ part, float* __restrict__ out) {
    int i = blockIdx.x * blockDim.x + threadIdx.x;
    const int Q = MDIM * HIDDEN / 4;
    float4 a = ((const float4*)part)[i];
    float4 b = ((const float4*)part)[i + Q];
    float4 o;
    o.x = a.x + b.x; o.y = a.y + b.y; o.z = a.z + b.z; o.w = a.w + b.w;
    ((float4*)out)[i] = o;
}

// ---------------- launch ----------------

extern "C" void kernel_launch(void* const* d_in, const int* in_sizes, int n_in,
                              void* d_out, int out_size, void* d_ws, size_t ws_size,
                              hipStream_t stream) {
    (void)in_sizes; (void)n_in; (void)out_size; (void)ws_size;

    const float* x  = (const float*)d_in[0];
    const uint32_t* qw1 = (const uint32_t*)d_in[1];
    const float* s1 = (const float*)d_in[2];
    const float* z1 = (const float*)d_in[3];
    const uint32_t* qw3 = (const uint32_t*)d_in[4];
    const float* s3 = (const float*)d_in[5];
    const float* z3 = (const float*)d_in[6];
    const uint32_t* qw2 = (const uint32_t*)d_in[7];
    const float* s2 = (const float*)d_in[8];
    const float* z2 = (const float*)d_in[9];
    float* out = (float*)d_out;

    // ws: xb 4.19M | sz1 3.67M | sz3 3.67M | sz2 3.67M | h(f16) 14.68M | part 16.78M
    char* ws = (char*)d_ws;
    ushort*   xb   = (ushort*)ws;
    uint32_t* szp1 = (uint32_t*)(ws + (size_t)MDIM * HIDDEN * 2);
    uint32_t* szp3 = szp1 + (size_t)G1 * HIDDEN;
    uint32_t* szp2 = szp3 + (size_t)G1 * HIDDEN;
    ushort*   hbuf = (ushort*)(szp2 + (size_t)G2 * FFN);
    float*    part = (float*)((char*)hbuf + (size_t)MDIM * FFN * 2);

    cvt_x_kernel<<<(MDIM * HIDDEN / 4) / 256, 256, 0, stream>>>(x, xb);
    build_sz_kernel<<<(G1 * HIDDEN / 2) / 256, 256, 0, stream>>>(s1, z1, szp1);
    build_sz_kernel<<<(G1 * HIDDEN / 2) / 256, 256, 0, stream>>>(s3, z3, szp3);
    build_sz_kernel<<<(G2 * FFN / 2) / 256, 256, 0, stream>>>(s2, z2, szp2);

    gemm_gateup<<<(FFN / 32) * (MDIM / 256), 256, 0, stream>>>(xb, qw1, szp1, qw3, szp3, hbuf);
    gemm_down<<<2 * (MDIM / 128) * (HIDDEN / 32), 256, 0, stream>>>(hbuf, qw2, szp2, part);
    reduce_out<<<(MDIM * HIDDEN / 4) / 256, 256, 0, stream>>>(part, out);
}

// Round 8
// 404.326 us; speedup vs baseline: 1.6704x; 1.6704x over previous
//
#include <hip/hip_runtime.h>
#include <hip/hip_fp16.h>
#include <stdint.h>

#define HIDDEN 4096
#define FFN    14336
#define MDIM   512
#define G1     224   // FFN / 64
#define G2     64    // HIDDEN / 64
#define BK     64

typedef _Float16 f16x8 __attribute__((ext_vector_type(8)));
typedef float f32x4 __attribute__((ext_vector_type(4)));

// async global->LDS, 16B per lane; LDS dest = wave-uniform base + lane*16
__device__ __forceinline__ void gl_lds16(const void* g, void* l) {
    __builtin_amdgcn_global_load_lds(
        (const __attribute__((address_space(1))) uint32_t*)g,
        (__attribute__((address_space(3))) uint32_t*)l, 16, 0, 0);
}

#define SCHED0() __builtin_amdgcn_sched_barrier(0);
#define LGKM_BAR()                                            \
    asm volatile("s_waitcnt lgkmcnt(0)" ::: "memory");        \
    __builtin_amdgcn_s_barrier();                             \
    __builtin_amdgcn_sched_barrier(0);

// ---------------- prep kernels ----------------

__global__ void cvt_x_kernel(const float* __restrict__ x, ushort* __restrict__ xb) {
    int i = blockIdx.x * blockDim.x + threadIdx.x;   // one float4 per thread
    float4 v = ((const float4*)x)[i];
    __half2 a = __floats2half2_rn(v.x, v.y);
    __half2 b = __floats2half2_rn(v.z, v.w);
    ((uint2*)xb)[i] = make_uint2(__builtin_bit_cast(uint32_t, a),
                                 __builtin_bit_cast(uint32_t, b));
}

// out[2i] = {f16(s0), f16(s1)}, out[2i+1] = {f16(-z0*s0), f16(-z1*s1)}
__global__ void build_sz_kernel(const float* __restrict__ s, const float* __restrict__ z,
                                uint32_t* __restrict__ outp) {
    int i = blockIdx.x * blockDim.x + threadIdx.x;
    float s0 = s[2 * i], s1 = s[2 * i + 1];
    float z0 = z[2 * i], z1 = z[2 * i + 1];
    __half2 hs = __floats2half2_rn(s0, s1);
    __half2 hn = __floats2half2_rn(-z0 * s0, -z1 * s1);
    ((uint2*)outp)[i] = make_uint2(__builtin_bit_cast(uint32_t, hs),
                                   __builtin_bit_cast(uint32_t, hn));
}

// dequant 2 codes -> packed f16 pair: table-select via v_perm + v_pk_fma_f16
__device__ __forceinline__ uint32_t deq2(uint32_t w0, uint32_t w1, uint32_t sh,
                                         uint32_t spair, uint32_t npair) {
    uint32_t c0 = (w0 >> sh) & 3u;
    uint32_t c1 = (w1 >> sh) & 3u;
    uint32_t sel = 0x01000100u + c0 * 0x0202u + c1 * 0x02020000u;
    uint32_t codes = __builtin_amdgcn_perm(0x42004000u, 0x3C000000u, sel); // f16{0,1,2,3}
    __half2 r = __hfma2(__builtin_bit_cast(__half2, codes),
                        __builtin_bit_cast(__half2, spair),
                        __builtin_bit_cast(__half2, npair));
    return __builtin_bit_cast(uint32_t, r);
}

// ---------------- GEMM A: gate/up fused + SwiGLU -> h (f16) ----------------
// BM=128, BN=32, BK=64, 4 waves stacked in M (wave tile 32x32).
// A: global_load_lds dbuf (32KB). B: dbuf LDS dequant (16KB). 48KB -> 3 blocks/CU.
// Single barrier per K-step: {GLDA(t+1) || DEQ(t+1->alt) || LD(t+3) || COMP(t)}.

__global__ __launch_bounds__(256, 3)
void gemm_gateup(const ushort* __restrict__ xb, const uint32_t* __restrict__ qw1,
                 const uint32_t* __restrict__ sz1, const uint32_t* __restrict__ qw3,
                 const uint32_t* __restrict__ sz3, ushort* __restrict__ hbuf) {
    __shared__ ushort sAl[2][128 * 64];   // 32 KB
    __shared__ ushort sB1[2][32 * 64];    // 8 KB
    __shared__ ushort sB2[2][32 * 64];    // 8 KB

    const int tid = threadIdx.x;
    // XCD swizzle: 1792 = 8 x 224; mt fast (mt quads share B inputs in L2)
    const int idx = ((blockIdx.x & 7) * 224) + (blockIdx.x >> 3);
    const int mt = idx & 3, nt = idx >> 2;       // mt 0..3, nt 0..447
    const int m0 = mt * 128, n0 = nt * 32;

    const int lane = tid & 63, w = tid >> 6;
    const int wm = w * 32;                       // wave m-offset
    const int frow = lane & 15, fk = (lane >> 4) * 8;
    const int sw = (frow & 7) << 3;              // read-side XOR swizzle

    // A gload source (pre-swizzled col chunk; linear LDS dest + swizzled read)
    const int qs = (lane & 7) ^ ((lane >> 3) & 7);
    const ushort* apS[4];
#pragma unroll
    for (int s = 0; s < 4; ++s) {
        int r = s * 32 + w * 8 + (lane >> 3);
        apS[s] = xb + (size_t)(m0 + r) * HIDDEN + qs * 8;
    }

    // B staging: threads 0-127 gate, 128-255 up; 2 rows x 8 k each
    const int bi = tid & 127;
    const int rp = bi >> 3;                      // 0..15 row-pair
    const int kc = (bi & 7) * 8;
    const int row0 = rp * 2;
    const int g0 = (n0 + row0) % G1;             // even, <=222; g0+1 no wrap
    const uint32_t* qp = (tid < 128 ? qw1 : qw3) + (size_t)(n0 / 4 + (rp >> 1)) * HIDDEN + kc;
    const uint32_t* zp = (tid < 128 ? sz1 : sz3) + (size_t)g0 * HIDDEN + kc;
    ushort (*sB)[32 * 64] = (tid < 128) ? sB1 : sB2;
    const uint32_t sh0 = 6u - 4u * (uint32_t)(rp & 1);

    f32x4 accG[2][2], accU[2][2];
#pragma unroll
    for (int i = 0; i < 2; ++i)
#pragma unroll
        for (int j = 0; j < 2; ++j) {
            accG[i][j] = (f32x4){0.f, 0.f, 0.f, 0.f};
            accU[i][j] = (f32x4){0.f, 0.f, 0.f, 0.f};
        }

    uint4 pwA0, pwA1, pzA0, pzA1, pzA2, pzA3;   // set A
    uint4 pwB0, pwB1, pzB0, pzB1, pzB2, pzB3;   // set B

#define GU_GLDA(k0d, wbuf)                                                     \
    { _Pragma("unroll")                                                        \
      for (int s = 0; s < 4; ++s)                                              \
          gl_lds16(apS[s] + (k0d), &sAl[wbuf][(s * 256 + w * 64) * 8]); }

#define GU_LD(PW0, PW1, PZ0, PZ1, PZ2, PZ3, k0q)                               \
    PW0 = *(const uint4*)(qp + (k0q));                                         \
    PW1 = *(const uint4*)(qp + (k0q) + 4);                                     \
    PZ0 = *(const uint4*)(zp + (k0q));                                         \
    PZ1 = *(const uint4*)(zp + (k0q) + 4);                                     \
    PZ2 = *(const uint4*)(zp + HIDDEN + (k0q));                                \
    PZ3 = *(const uint4*)(zp + HIDDEN + (k0q) + 4);

#define GU_DEQ(wbuf, PW0, PW1, PZ0, PZ1, PZ2, PZ3)                             \
    { const uint32_t wv[8] = {(PW0).x, (PW0).y, (PW0).z, (PW0).w,              \
                              (PW1).x, (PW1).y, (PW1).z, (PW1).w};             \
      {   const uint32_t sp[4] = {(PZ0).x, (PZ0).z, (PZ1).x, (PZ1).z};         \
          const uint32_t np[4] = {(PZ0).y, (PZ0).w, (PZ1).y, (PZ1).w};         \
          uint32_t o[4];                                                       \
          _Pragma("unroll")                                                    \
          for (int j = 0; j < 4; ++j)                                          \
              o[j] = deq2(wv[2*j], wv[2*j+1], sh0, sp[j], np[j]);              \
          *(uint4*)&sB[wbuf][row0 * 64 + (kc ^ ((row0 & 7) << 3))] =           \
              make_uint4(o[0], o[1], o[2], o[3]);                              \
      }                                                                        \
      {   const uint32_t sp[4] = {(PZ2).x, (PZ2).z, (PZ3).x, (PZ3).z};         \
          const uint32_t np[4] = {(PZ2).y, (PZ2).w, (PZ3).y, (PZ3).w};         \
          uint32_t o[4];                                                       \
          _Pragma("unroll")                                                    \
          for (int j = 0; j < 4; ++j)                                          \
              o[j] = deq2(wv[2*j], wv[2*j+1], sh0 - 2u, sp[j], np[j]);         \
          const int row1 = row0 + 1;                                           \
          *(uint4*)&sB[wbuf][row1 * 64 + (kc ^ ((row1 & 7) << 3))] =           \
              make_uint4(o[0], o[1], o[2], o[3]);                              \
      } }

#define GU_COMP(rbuf)                                                          \
    { _Pragma("unroll")                                                        \
      for (int kk = 0; kk < 2; ++kk) {                                         \
          const int col = ((kk * 32) + fk) ^ sw;                               \
          f16x8 af[2], bg[2], bu[2];                                           \
          _Pragma("unroll")                                                    \
          for (int i = 0; i < 2; ++i)                                          \
              af[i] = *(const f16x8*)&sAl[rbuf][(wm + i * 16 + frow) * 64 + col]; \
          bg[0] = *(const f16x8*)&sB1[rbuf][frow * 64 + col];                  \
          bg[1] = *(const f16x8*)&sB1[rbuf][(16 + frow) * 64 + col];           \
          bu[0] = *(const f16x8*)&sB2[rbuf][frow * 64 + col];                  \
          bu[1] = *(const f16x8*)&sB2[rbuf][(16 + frow) * 64 + col];           \
          _Pragma("unroll")                                                    \
          for (int mi = 0; mi < 2; ++mi)                                       \
              _Pragma("unroll")                                                \
              for (int ni = 0; ni < 2; ++ni) {                                 \
                  accG[mi][ni] = __builtin_amdgcn_mfma_f32_16x16x32_f16(af[mi], bg[ni], accG[mi][ni], 0, 0, 0); \
                  accU[mi][ni] = __builtin_amdgcn_mfma_f32_16x16x32_f16(af[mi], bu[ni], accU[mi][ni], 0, 0, 0); \
              } } }

// one barrier per K-step; DEQ(t+1) and COMP(t) share the scheduling window
#define GU_STEP(k0s, WBUF, RBUF, PW0, PW1, PZ0, PZ1, PZ2, PZ3, DOPF, VMS)      \
    { GU_GLDA((k0s) + BK, WBUF) SCHED0()                                       \
      GU_DEQ(WBUF, PW0, PW1, PZ0, PZ1, PZ2, PZ3)                               \
      if (DOPF) { GU_LD(PW0, PW1, PZ0, PZ1, PZ2, PZ3, (k0s) + 3 * BK) }        \
      GU_COMP(RBUF)                                                            \
      asm volatile("s_waitcnt vmcnt(" VMS ") lgkmcnt(0)" ::: "memory");        \
      __builtin_amdgcn_s_barrier();                                            \
      SCHED0() }

    // prologue: tile 0 in LDS, qw(1) in setA, qw(2) in setB
    GU_GLDA(0, 0)
    GU_LD(pwA0, pwA1, pzA0, pzA1, pzA2, pzA3, 0)
    asm volatile("s_waitcnt vmcnt(0)" ::: "memory"); SCHED0()
    GU_DEQ(0, pwA0, pwA1, pzA0, pzA1, pzA2, pzA3)
    GU_LD(pwA0, pwA1, pzA0, pzA1, pzA2, pzA3, BK)
    GU_LD(pwB0, pwB1, pzB0, pzB1, pzB2, pzB3, 2 * BK)
    asm volatile("s_waitcnt lgkmcnt(0)" ::: "memory");
    __builtin_amdgcn_s_barrier();
    SCHED0()

    for (int t = 0; t < 60; t += 2) {
        GU_STEP(t * BK,       1, 0, pwA0, pwA1, pzA0, pzA1, pzA2, pzA3, 1, "6")
        GU_STEP((t + 1) * BK, 0, 1, pwB0, pwB1, pzB0, pzB1, pzB2, pzB3, 1, "6")
    }
    GU_STEP(60 * BK, 1, 0, pwA0, pwA1, pzA0, pzA1, pzA2, pzA3, 1, "6")
    GU_STEP(61 * BK, 0, 1, pwB0, pwB1, pzB0, pzB1, pzB2, pzB3, 0, "0")
    GU_STEP(62 * BK, 1, 0, pwA0, pwA1, pzA0, pzA1, pzA2, pzA3, 0, "0")
    GU_COMP(1)   // tile 63

    // ---- epilogue: silu(gate)*up -> LDS -> coalesced f16 stores ----
    ushort* sE = &sAl[0][0];   // 128 x 32 staging (buf0 reads all drained at barrier 62)
    const int rb = (lane >> 4) * 4, cb = lane & 15;
#pragma unroll
    for (int mi = 0; mi < 2; ++mi)
#pragma unroll
        for (int ni = 0; ni < 2; ++ni) {
            f32x4 g = accG[mi][ni], u = accU[mi][ni];
            const int row = wm + mi * 16 + rb;
            const int colx = ni * 16 + cb;
#pragma unroll
            for (int r = 0; r < 4; ++r) {
                float gv = g[r];
                float hv = __fdividef(gv, 1.0f + __expf(-gv)) * u[r];
                __half hh = __float2half(hv);
                sE[(row + r) * 32 + colx] = __builtin_bit_cast(ushort, hh);
            }
        }
    __syncthreads();
    {
        const int row = tid >> 1, c0 = (tid & 1) * 16;
        ushort* dst = hbuf + (size_t)(m0 + row) * FFN + n0 + c0;
        const ushort* src = sE + row * 32 + c0;
        *(uint4*)(dst)     = *(const uint4*)(src);
        *(uint4*)(dst + 8) = *(const uint4*)(src + 8);
    }
#undef GU_GLDA
#undef GU_LD
#undef GU_DEQ
#undef GU_COMP
#undef GU_STEP
}

// ---------------- GEMM B: out_partial = h @ w2^T (split-K = 2) ----------------
// BM=128, BN=32, BK=64, 4 waves stacked in M; 40KB LDS -> 4 blocks/CU.

__global__ __launch_bounds__(256, 4)
void gemm_down(const ushort* __restrict__ hb, const uint32_t* __restrict__ qw2,
               const uint32_t* __restrict__ sz2, float* __restrict__ part) {
    __shared__ ushort sAl[2][128 * 64];   // 32 KB
    __shared__ ushort sBd[2][32 * 64];    // 8 KB

    const int tid = threadIdx.x;
    // 1024 = 8 x 128 XCD swizzle; mt fast, sk slowest
    const int idx = ((blockIdx.x & 7) * 128) + (blockIdx.x >> 3);
    const int mt = idx & 3, nt = (idx >> 2) & 127, sk = idx >> 9;
    const int m0 = mt * 128, n0 = nt * 32;
    const int kbeg = sk * (FFN / 2);

    const int lane = tid & 63, w = tid >> 6;
    const int wm = w * 32;
    const int frow = lane & 15, fk = (lane >> 4) * 8;
    const int sw = (frow & 7) << 3;

    const int qs = (lane & 7) ^ ((lane >> 3) & 7);
    const ushort* apS[4];
#pragma unroll
    for (int s = 0; s < 4; ++s) {
        int r = s * 32 + w * 8 + (lane >> 3);
        apS[s] = hb + (size_t)(m0 + r) * FFN + kbeg + qs * 8;
    }

    // B staging: 1 row x 8 k per thread (32 rows x 8 chunks = 256)
    const int r = tid >> 3;               // 0..31
    const int kc = (tid & 7) * 8;
    const int g = ((nt & 1) * 32) + r;    // (n0 + r) % 64
    const uint32_t* qp = qw2 + (size_t)(n0 / 4 + (r >> 2)) * FFN + kbeg + kc;
    const uint32_t* zp = sz2 + (size_t)g * FFN + kbeg + kc;
    const uint32_t sh = 6u - 2u * (uint32_t)(r & 3);

    f32x4 acc[2][2];
#pragma unroll
    for (int i = 0; i < 2; ++i)
#pragma unroll
        for (int j = 0; j < 2; ++j) acc[i][j] = (f32x4){0.f, 0.f, 0.f, 0.f};

    uint4 pwA0, pwA1, pzA0, pzA1;
    uint4 pwB0, pwB1, pzB0, pzB1;

#define GD_GLDA(k0d, wbuf)                                                     \
    { _Pragma("unroll")                                                        \
      for (int s = 0; s < 4; ++s)                                              \
          gl_lds16(apS[s] + (k0d), &sAl[wbuf][(s * 256 + w * 64) * 8]); }

#define GD_LD(PW0, PW1, PZ0, PZ1, k0q)                                         \
    PW0 = *(const uint4*)(qp + (k0q));                                         \
    PW1 = *(const uint4*)(qp + (k0q) + 4);                                     \
    PZ0 = *(const uint4*)(zp + (k0q));                                         \
    PZ1 = *(const uint4*)(zp + (k0q) + 4);

#define GD_DEQ(wbuf, PW0, PW1, PZ0, PZ1)                                       \
    { const uint32_t wv[8] = {(PW0).x, (PW0).y, (PW0).z, (PW0).w,              \
                              (PW1).x, (PW1).y, (PW1).z, (PW1).w};             \
      const uint32_t sp[4] = {(PZ0).x, (PZ0).z, (PZ1).x, (PZ1).z};             \
      const uint32_t np[4] = {(PZ0).y, (PZ0).w, (PZ1).y, (PZ1).w};             \
      uint32_t o[4];                                                           \
      _Pragma("unroll")                                                        \
      for (int j = 0; j < 4; ++j)                                              \
          o[j] = deq2(wv[2*j], wv[2*j+1], sh, sp[j], np[j]);                   \
      *(uint4*)&sBd[wbuf][r * 64 + (kc ^ ((r & 7) << 3))] =                    \
          make_uint4(o[0], o[1], o[2], o[3]); }

#define GD_COMP(rbuf)                                                          \
    { _Pragma("unroll")                                                        \
      for (int kk = 0; kk < 2; ++kk) {                                         \
          const int col = ((kk * 32) + fk) ^ sw;                               \
          f16x8 af[2], bf[2];                                                  \
          _Pragma("unroll")                                                    \
          for (int i = 0; i < 2; ++i)                                          \
              af[i] = *(const f16x8*)&sAl[rbuf][(wm + i * 16 + frow) * 64 + col]; \
          bf[0] = *(const f16x8*)&sBd[rbuf][frow * 64 + col];                  \
          bf[1] = *(const f16x8*)&sBd[rbuf][(16 + frow) * 64 + col];           \
          _Pragma("unroll")                                                    \
          for (int mi = 0; mi < 2; ++mi)                                       \
              _Pragma("unroll")                                                \
              for (int ni = 0; ni < 2; ++ni)                                   \
                  acc[mi][ni] = __builtin_amdgcn_mfma_f32_16x16x32_f16(af[mi], bf[ni], acc[mi][ni], 0, 0, 0); \
      } }

#define GD_STEP(k0s, WBUF, RBUF, PW0, PW1, PZ0, PZ1, DOPF, VMS)                \
    { GD_GLDA((k0s) + BK, WBUF) SCHED0()                                       \
      GD_DEQ(WBUF, PW0, PW1, PZ0, PZ1)                                         \
      if (DOPF) { GD_LD(PW0, PW1, PZ0, PZ1, (k0s) + 3 * BK) }                  \
      GD_COMP(RBUF)                                                            \
      asm volatile("s_waitcnt vmcnt(" VMS ") lgkmcnt(0)" ::: "memory");        \
      __builtin_amdgcn_s_barrier();                                            \
      SCHED0() }

    GD_GLDA(0, 0)
    GD_LD(pwA0, pwA1, pzA0, pzA1, 0)
    asm volatile("s_waitcnt vmcnt(0)" ::: "memory"); SCHED0()
    GD_DEQ(0, pwA0, pwA1, pzA0, pzA1)
    GD_LD(pwA0, pwA1, pzA0, pzA1, BK)
    GD_LD(pwB0, pwB1, pzB0, pzB1, 2 * BK)
    asm volatile("s_waitcnt lgkmcnt(0)" ::: "memory");
    __builtin_amdgcn_s_barrier();
    SCHED0()

    for (int t = 0; t < 108; t += 2) {
        GD_STEP(t * BK,       1, 0, pwA0, pwA1, pzA0, pzA1, 1, "4")
        GD_STEP((t + 1) * BK, 0, 1, pwB0, pwB1, pzB0, pzB1, 1, "4")
    }
    GD_STEP(108 * BK, 1, 0, pwA0, pwA1, pzA0, pzA1, 1, "4")
    GD_STEP(109 * BK, 0, 1, pwB0, pwB1, pzB0, pzB1, 0, "0")
    GD_STEP(110 * BK, 1, 0, pwA0, pwA1, pzA0, pzA1, 0, "0")
    GD_COMP(1)   // tile 111

    float* pp = part + (size_t)sk * MDIM * HIDDEN;
    const int rb = (lane >> 4) * 4, cb = lane & 15;
#pragma unroll
    for (int mi = 0; mi < 2; ++mi)
#pragma unroll
        for (int ni = 0; ni < 2; ++ni) {
            f32x4 a = acc[mi][ni];
            const int mm = m0 + wm + mi * 16 + rb;
            const int nn = n0 + ni * 16 + cb;
#pragma unroll
            for (int rr = 0; rr < 4; ++rr) pp[(size_t)(mm + rr) * HIDDEN + nn] = a[rr];
        }
#undef GD_GLDA
#undef GD_LD
#undef GD_DEQ
#undef GD_COMP
#undef GD_STEP
}

// ---------------- reduce split-K partials ----------------

__global__ void reduce_out(const float* __restrict__ part, float* __restrict__ out) {
    int i = blockIdx.x * blockDim.x + threadIdx.x;
    const int Q = MDIM * HIDDEN / 4;
    float4 a = ((const float4*)part)[i];
    float4 b = ((const float4*)part)[i + Q];
    float4 o;
    o.x = a.x + b.x; o.y = a.y + b.y; o.z = a.z + b.z; o.w = a.w + b.w;
    ((float4*)out)[i] = o;
}

// ---------------- launch ----------------

extern "C" void kernel_launch(void* const* d_in, const int* in_sizes, int n_in,
                              void* d_out, int out_size, void* d_ws, size_t ws_size,
                              hipStream_t stream) {
    (void)in_sizes; (void)n_in; (void)out_size; (void)ws_size;

    const float* x  = (const float*)d_in[0];
    const uint32_t* qw1 = (const uint32_t*)d_in[1];
    const float* s1 = (const float*)d_in[2];
    const float* z1 = (const float*)d_in[3];
    const uint32_t* qw3 = (const uint32_t*)d_in[4];
    const float* s3 = (const float*)d_in[5];
    const float* z3 = (const float*)d_in[6];
    const uint32_t* qw2 = (const uint32_t*)d_in[7];
    const float* s2 = (const float*)d_in[8];
    const float* z2 = (const float*)d_in[9];
    float* out = (float*)d_out;

    // ws: xb 4.19M | sz1 3.67M | sz3 3.67M | sz2 3.67M | h(f16) 14.68M | part 16.78M
    char* ws = (char*)d_ws;
    ushort*   xb   = (ushort*)ws;
    uint32_t* szp1 = (uint32_t*)(ws + (size_t)MDIM * HIDDEN * 2);
    uint32_t* szp3 = szp1 + (size_t)G1 * HIDDEN;
    uint32_t* szp2 = szp3 + (size_t)G1 * HIDDEN;
    ushort*   hbuf = (ushort*)(szp2 + (size_t)G2 * FFN);
    float*    part = (float*)((char*)hbuf + (size_t)MDIM * FFN * 2);

    cvt_x_kernel<<<(MDIM * HIDDEN / 4) / 256, 256, 0, stream>>>(x, xb);
    build_sz_kernel<<<(G1 * HIDDEN / 2) / 256, 256, 0, stream>>>(s1, z1, szp1);
    build_sz_kernel<<<(G1 * HIDDEN / 2) / 256, 256, 0, stream>>>(s3, z3, szp3);
    build_sz_kernel<<<(G2 * FFN / 2) / 256, 256, 0, stream>>>(s2, z2, szp2);

    gemm_gateup<<<(FFN / 32) * (MDIM / 128), 256, 0, stream>>>(xb, qw1, szp1, qw3, szp3, hbuf);
    gemm_down<<<2 * (MDIM / 128) * (HIDDEN / 32), 256, 0, stream>>>(hbuf, qw2, szp2, part);
    reduce_out<<<(MDIM * HIDDEN / 4) / 256, 256, 0, stream>>>(part, out);
}

// Round 9
// 272.973 us; speedup vs baseline: 2.4742x; 1.4812x over previous
//
#include <hip/hip_runtime.h>
#include <hip/hip_fp16.h>
#include <stdint.h>

#define HIDDEN 4096
#define FFN    14336
#define MDIM   512
#define G1     224   // FFN / 64
#define G2     64    // HIDDEN / 64
#define BK     64
#define KB_H   128   // HIDDEN/32
#define KB_F   448   // FFN/32

typedef _Float16 f16x8 __attribute__((ext_vector_type(8)));
typedef float f32x4 __attribute__((ext_vector_type(4)));

#define SCHED0() __builtin_amdgcn_sched_barrier(0);
#define LGKM_BAR()                                            \
    asm volatile("s_waitcnt lgkmcnt(0)" ::: "memory");        \
    __builtin_amdgcn_s_barrier();                             \
    __builtin_amdgcn_sched_barrier(0);

// ---------------- prep kernels ----------------

// x (f32, row-major) -> xbp (f16, MFMA-fragment-major):
// xbp[((mb*KB_H + kb)*64 + lane)*8 + e] = x[mb*16 + (lane&15)][kb*32 + (lane>>4)*8 + e]
__global__ void cvt_xp_kernel(const float* __restrict__ x, ushort* __restrict__ xbp) {
    int i = blockIdx.x * blockDim.x + threadIdx.x;   // [0, MDIM*HIDDEN/8)
    int ls = i & 63;
    int kb = (i >> 6) & (KB_H - 1);
    int mb = i >> 13;                                // 64*128 = 8192 = 1<<13
    int row = mb * 16 + (ls & 15);
    int col = kb * 32 + (ls >> 4) * 8;
    const float4* src = (const float4*)&x[(size_t)row * HIDDEN + col];
    float4 v0 = src[0], v1 = src[1];
    __half2 h0 = __floats2half2_rn(v0.x, v0.y);
    __half2 h1 = __floats2half2_rn(v0.z, v0.w);
    __half2 h2 = __floats2half2_rn(v1.x, v1.y);
    __half2 h3 = __floats2half2_rn(v1.z, v1.w);
    uint4 o = make_uint4(__builtin_bit_cast(uint32_t, h0), __builtin_bit_cast(uint32_t, h1),
                         __builtin_bit_cast(uint32_t, h2), __builtin_bit_cast(uint32_t, h3));
    ((uint4*)xbp)[i] = o;
}

// out[2i] = {f16(s0), f16(s1)}, out[2i+1] = {f16(-z0*s0), f16(-z1*s1)}
__global__ void build_sz_kernel(const float* __restrict__ s, const float* __restrict__ z,
                                uint32_t* __restrict__ outp) {
    int i = blockIdx.x * blockDim.x + threadIdx.x;
    float s0 = s[2 * i], s1 = s[2 * i + 1];
    float z0 = z[2 * i], z1 = z[2 * i + 1];
    __half2 hs = __floats2half2_rn(s0, s1);
    __half2 hn = __floats2half2_rn(-z0 * s0, -z1 * s1);
    ((uint2*)outp)[i] = make_uint2(__builtin_bit_cast(uint32_t, hs),
                                   __builtin_bit_cast(uint32_t, hn));
}

// dequant 2 codes -> packed f16 pair: table-select via v_perm + v_pk_fma_f16
__device__ __forceinline__ uint32_t deq2(uint32_t w0, uint32_t w1, uint32_t sh,
                                         uint32_t spair, uint32_t npair) {
    uint32_t c0 = (w0 >> sh) & 3u;
    uint32_t c1 = (w1 >> sh) & 3u;
    uint32_t sel = 0x01000100u + c0 * 0x0202u + c1 * 0x02020000u;
    uint32_t codes = __builtin_amdgcn_perm(0x42004000u, 0x3C000000u, sel); // f16{0,1,2,3}
    __half2 r = __hfma2(__builtin_bit_cast(__half2, codes),
                        __builtin_bit_cast(__half2, spair),
                        __builtin_bit_cast(__half2, npair));
    return __builtin_bit_cast(uint32_t, r);
}

// ---------------- GEMM A: gate/up fused + SwiGLU -> hp (f16 frag-major) ----------------
// BM=256, BN=32, BK=64, 4 waves M-stacked (wave 64x32). A: direct frag-major
// global->reg, prefetched 1 step. B: reg-prefetch 2-deep -> dequant -> dbuf LDS.
// Barrier per step is lgkmcnt-only (B handoff); no vmcnt coupling.

__global__ __launch_bounds__(256, 2)
void gemm_gateup(const ushort* __restrict__ xbp, const uint32_t* __restrict__ qw1,
                 const uint32_t* __restrict__ sz1, const uint32_t* __restrict__ qw3,
                 const uint32_t* __restrict__ sz3, ushort* __restrict__ hp) {
    __shared__ ushort sB1[2][32 * 64];    // 8 KB
    __shared__ ushort sB2[2][32 * 64];    // 8 KB
    __shared__ ushort sE[256 * 32];       // 16 KB epilogue staging

    const int tid = threadIdx.x;
    // XCD swizzle: 896 = 8 x 112; mt fast
    const int idx = ((blockIdx.x & 7) * 112) + (blockIdx.x >> 3);
    const int mt = idx & 1, nt = idx >> 1;
    const int m0 = mt * 256, n0 = nt * 32;

    const int lane = tid & 63, w = tid >> 6;
    const int wm = w * 64;
    const int frow = lane & 15, fk = (lane >> 4) * 8;
    const int sw = (frow & 7) << 3;       // B read-side XOR swizzle

    // A frag-major base offsets (ushort elements)
    uint32_t abase[4];
#pragma unroll
    for (int mi = 0; mi < 4; ++mi)
        abase[mi] = (uint32_t)(((m0 >> 4) + w * 4 + mi) * KB_H) * 512 + lane * 8;

    // B staging: threads 0-127 gate, 128-255 up; 2 rows x 8 k each
    const int bi = tid & 127;
    const int rp = bi >> 3;
    const int kc = (bi & 7) * 8;
    const int row0 = rp * 2;
    const int g0 = (n0 + row0) % G1;      // even, <=222; g0+1 no wrap
    const uint32_t* qp = (tid < 128 ? qw1 : qw3) + (size_t)(n0 / 4 + (rp >> 1)) * HIDDEN + kc;
    const uint32_t* zp = (tid < 128 ? sz1 : sz3) + (size_t)g0 * HIDDEN + kc;
    ushort (*sB)[32 * 64] = (tid < 128) ? sB1 : sB2;
    const uint32_t sh0 = 6u - 4u * (uint32_t)(rp & 1);

    f32x4 accG[4][2], accU[4][2];
#pragma unroll
    for (int i = 0; i < 4; ++i)
#pragma unroll
        for (int j = 0; j < 2; ++j) {
            accG[i][j] = (f32x4){0.f, 0.f, 0.f, 0.f};
            accU[i][j] = (f32x4){0.f, 0.f, 0.f, 0.f};
        }

    f16x8 afA[8], afB[8];                 // A-frag sets (static idx mi*2+kk)
    uint4 pwA0, pwA1, pzA0, pzA1, pzA2, pzA3;
    uint4 pwB0, pwB1, pzB0, pzB1, pzB2, pzB3;

#define GU_LDA(AF, tt)                                                         \
    { _Pragma("unroll")                                                        \
      for (int mi = 0; mi < 4; ++mi)                                           \
          _Pragma("unroll")                                                    \
          for (int kk = 0; kk < 2; ++kk)                                       \
              AF[mi * 2 + kk] =                                                \
                  *(const f16x8*)&xbp[abase[mi] + (uint32_t)((tt) * 2 + kk) * 512]; }

#define GU_LD(PW0, PW1, PZ0, PZ1, PZ2, PZ3, k0q)                               \
    PW0 = *(const uint4*)(qp + (k0q));                                         \
    PW1 = *(const uint4*)(qp + (k0q) + 4);                                     \
    PZ0 = *(const uint4*)(zp + (k0q));                                         \
    PZ1 = *(const uint4*)(zp + (k0q) + 4);                                     \
    PZ2 = *(const uint4*)(zp + HIDDEN + (k0q));                                \
    PZ3 = *(const uint4*)(zp + HIDDEN + (k0q) + 4);

#define GU_DEQ(wbuf, PW0, PW1, PZ0, PZ1, PZ2, PZ3)                             \
    { const uint32_t wv[8] = {(PW0).x, (PW0).y, (PW0).z, (PW0).w,              \
                              (PW1).x, (PW1).y, (PW1).z, (PW1).w};             \
      {   const uint32_t sp[4] = {(PZ0).x, (PZ0).z, (PZ1).x, (PZ1).z};         \
          const uint32_t np[4] = {(PZ0).y, (PZ0).w, (PZ1).y, (PZ1).w};         \
          uint32_t o[4];                                                       \
          _Pragma("unroll")                                                    \
          for (int j = 0; j < 4; ++j)                                          \
              o[j] = deq2(wv[2*j], wv[2*j+1], sh0, sp[j], np[j]);              \
          *(uint4*)&sB[wbuf][row0 * 64 + (kc ^ ((row0 & 7) << 3))] =           \
              make_uint4(o[0], o[1], o[2], o[3]);                              \
      }                                                                        \
      {   const uint32_t sp[4] = {(PZ2).x, (PZ2).z, (PZ3).x, (PZ3).z};         \
          const uint32_t np[4] = {(PZ2).y, (PZ2).w, (PZ3).y, (PZ3).w};         \
          uint32_t o[4];                                                       \
          _Pragma("unroll")                                                    \
          for (int j = 0; j < 4; ++j)                                          \
              o[j] = deq2(wv[2*j], wv[2*j+1], sh0 - 2u, sp[j], np[j]);         \
          const int row1 = row0 + 1;                                           \
          *(uint4*)&sB[wbuf][row1 * 64 + (kc ^ ((row1 & 7) << 3))] =           \
              make_uint4(o[0], o[1], o[2], o[3]);                              \
      } }

#define GU_COMP(AF, rbuf)                                                      \
    { _Pragma("unroll")                                                        \
      for (int kk = 0; kk < 2; ++kk) {                                         \
          const int col = ((kk * 32) + fk) ^ sw;                               \
          f16x8 bg0 = *(const f16x8*)&sB1[rbuf][frow * 64 + col];              \
          f16x8 bg1 = *(const f16x8*)&sB1[rbuf][(16 + frow) * 64 + col];       \
          f16x8 bu0 = *(const f16x8*)&sB2[rbuf][frow * 64 + col];              \
          f16x8 bu1 = *(const f16x8*)&sB2[rbuf][(16 + frow) * 64 + col];       \
          _Pragma("unroll")                                                    \
          for (int mi = 0; mi < 4; ++mi) {                                     \
              accG[mi][0] = __builtin_amdgcn_mfma_f32_16x16x32_f16(AF[mi*2+kk], bg0, accG[mi][0], 0, 0, 0); \
              accG[mi][1] = __builtin_amdgcn_mfma_f32_16x16x32_f16(AF[mi*2+kk], bg1, accG[mi][1], 0, 0, 0); \
              accU[mi][0] = __builtin_amdgcn_mfma_f32_16x16x32_f16(AF[mi*2+kk], bu0, accU[mi][0], 0, 0, 0); \
              accU[mi][1] = __builtin_amdgcn_mfma_f32_16x16x32_f16(AF[mi*2+kk], bu1, accU[mi][1], 0, 0, 0); \
          } } }

#define GU_STEP(tcur, AFW, AFR, WBUF, RBUF, PW0, PW1, PZ0, PZ1, PZ2, PZ3, DOLDA, DOLQ) \
    { if (DOLDA) { GU_LDA(AFW, (tcur) + 1) } SCHED0()                          \
      GU_DEQ(WBUF, PW0, PW1, PZ0, PZ1, PZ2, PZ3)                               \
      if (DOLQ) { GU_LD(PW0, PW1, PZ0, PZ1, PZ2, PZ3, ((tcur) + 3) * BK) }     \
      GU_COMP(AFR, RBUF)                                                       \
      LGKM_BAR() }

    // prologue: tile0 regs + A-frags; DEQ tile0 -> buf0; tile1/2 qw-sets in flight
    GU_LD(pwA0, pwA1, pzA0, pzA1, pzA2, pzA3, 0)
    GU_LDA(afA, 0)
    GU_DEQ(0, pwA0, pwA1, pzA0, pzA1, pzA2, pzA3)
    GU_LD(pwA0, pwA1, pzA0, pzA1, pzA2, pzA3, BK)
    GU_LD(pwB0, pwB1, pzB0, pzB1, pzB2, pzB3, 2 * BK)
    LGKM_BAR()

    for (int t = 0; t < 60; t += 2) {
        GU_STEP(t,     afB, afA, 1, 0, pwA0, pwA1, pzA0, pzA1, pzA2, pzA3, 1, 1)
        GU_STEP(t + 1, afA, afB, 0, 1, pwB0, pwB1, pzB0, pzB1, pzB2, pzB3, 1, 1)
    }
    GU_STEP(60, afB, afA, 1, 0, pwA0, pwA1, pzA0, pzA1, pzA2, pzA3, 1, 1)
    GU_STEP(61, afA, afB, 0, 1, pwB0, pwB1, pzB0, pzB1, pzB2, pzB3, 1, 0)
    GU_STEP(62, afB, afA, 1, 0, pwA0, pwA1, pzA0, pzA1, pzA2, pzA3, 1, 0)
    GU_COMP(afB, 1)   // tile 63

    // ---- epilogue: silu(gate)*up -> sE -> frag-major stores to hp ----
    const int rb = (lane >> 4) * 4, cb = lane & 15;
#pragma unroll
    for (int mi = 0; mi < 4; ++mi)
#pragma unroll
        for (int ni = 0; ni < 2; ++ni) {
            f32x4 g = accG[mi][ni], u = accU[mi][ni];
            const int row = wm + mi * 16 + rb;
            const int colx = ni * 16 + cb;
#pragma unroll
            for (int r = 0; r < 4; ++r) {
                float gv = g[r];
                float hv = __fdividef(gv, 1.0f + __expf(-gv)) * u[r];
                __half hh = __float2half(hv);
                sE[(row + r) * 32 + colx] = __builtin_bit_cast(ushort, hh);
            }
        }
    __syncthreads();
    {
#pragma unroll
        for (int j = 0; j < 4; ++j) {
            const int slot = tid + j * 256;          // [0,1024): 16 mb-blocks x 64 lanes
            const int mbi = slot >> 6, ls = slot & 63;
            uint4 v = *(const uint4*)&sE[(mbi * 16 + (ls & 15)) * 32 + (ls >> 4) * 8];
            *(uint4*)&hp[(size_t)(((m0 >> 4) + mbi) * KB_F + nt) * 512 + ls * 8] = v;
        }
    }
#undef GU_LDA
#undef GU_LD
#undef GU_DEQ
#undef GU_COMP
#undef GU_STEP
}

// ---------------- GEMM B: out_partial = hp @ w2^T (split-K = 2) ----------------
// BM=256, BN=32, BK=64; A direct frag-major from hp; B dbuf LDS dequant.

__global__ __launch_bounds__(256, 2)
void gemm_down(const ushort* __restrict__ hp, const uint32_t* __restrict__ qw2,
               const uint32_t* __restrict__ sz2, float* __restrict__ part) {
    __shared__ ushort sBd[2][32 * 64];    // 8 KB

    const int tid = threadIdx.x;
    // 512 = 8 x 64 XCD swizzle
    const int idx = ((blockIdx.x & 7) * 64) + (blockIdx.x >> 3);
    const int mt = idx & 1, nt = (idx >> 1) & 127, sk = idx >> 8;
    const int m0 = mt * 256, n0 = nt * 32;
    const int kb0 = sk * 224;             // kbeg/32

    const int lane = tid & 63, w = tid >> 6;
    const int wm = w * 64;
    const int frow = lane & 15, fk = (lane >> 4) * 8;
    const int sw = (frow & 7) << 3;

    uint32_t abase[4];
#pragma unroll
    for (int mi = 0; mi < 4; ++mi)
        abase[mi] = (uint32_t)(((m0 >> 4) + w * 4 + mi) * KB_F + kb0) * 512 + lane * 8;

    // B staging: 1 row x 8 k per thread
    const int r = tid >> 3;
    const int kc = (tid & 7) * 8;
    const int g = ((nt & 1) * 32) + r;    // (n0 + r) % 64
    const int kbeg = sk * (FFN / 2);
    const uint32_t* qp = qw2 + (size_t)(n0 / 4 + (r >> 2)) * FFN + kbeg + kc;
    const uint32_t* zp = sz2 + (size_t)g * FFN + kbeg + kc;
    const uint32_t sh = 6u - 2u * (uint32_t)(r & 3);

    f32x4 acc[4][2];
#pragma unroll
    for (int i = 0; i < 4; ++i)
#pragma unroll
        for (int j = 0; j < 2; ++j) acc[i][j] = (f32x4){0.f, 0.f, 0.f, 0.f};

    f16x8 afA[8], afB[8];
    uint4 pwA0, pwA1, pzA0, pzA1;
    uint4 pwB0, pwB1, pzB0, pzB1;

#define GD_LDA(AF, tt)                                                         \
    { _Pragma("unroll")                                                        \
      for (int mi = 0; mi < 4; ++mi)                                           \
          _Pragma("unroll")                                                    \
          for (int kk = 0; kk < 2; ++kk)                                       \
              AF[mi * 2 + kk] =                                                \
                  *(const f16x8*)&hp[abase[mi] + (uint32_t)((tt) * 2 + kk) * 512]; }

#define GD_LD(PW0, PW1, PZ0, PZ1, k0q)                                         \
    PW0 = *(const uint4*)(qp + (k0q));                                         \
    PW1 = *(const uint4*)(qp + (k0q) + 4);                                     \
    PZ0 = *(const uint4*)(zp + (k0q));                                         \
    PZ1 = *(const uint4*)(zp + (k0q) + 4);

#define GD_DEQ(wbuf, PW0, PW1, PZ0, PZ1)                                       \
    { const uint32_t wv[8] = {(PW0).x, (PW0).y, (PW0).z, (PW0).w,              \
                              (PW1).x, (PW1).y, (PW1).z, (PW1).w};             \
      const uint32_t sp[4] = {(PZ0).x, (PZ0).z, (PZ1).x, (PZ1).z};             \
      const uint32_t np[4] = {(PZ0).y, (PZ0).w, (PZ1).y, (PZ1).w};             \
      uint32_t o[4];                                                           \
      _Pragma("unroll")                                                        \
      for (int j = 0; j < 4; ++j)                                              \
          o[j] = deq2(wv[2*j], wv[2*j+1], sh, sp[j], np[j]);                   \
      *(uint4*)&sBd[wbuf][r * 64 + (kc ^ ((r & 7) << 3))] =                    \
          make_uint4(o[0], o[1], o[2], o[3]); }

#define GD_COMP(AF, rbuf)                                                      \
    { _Pragma("unroll")                                                        \
      for (int kk = 0; kk < 2; ++kk) {                                         \
          const int col = ((kk * 32) + fk) ^ sw;                               \
          f16x8 bf0 = *(const f16x8*)&sBd[rbuf][frow * 64 + col];              \
          f16x8 bf1 = *(const f16x8*)&sBd[rbuf][(16 + frow) * 64 + col];       \
          _Pragma("unroll")                                                    \
          for (int mi = 0; mi < 4; ++mi) {                                     \
              acc[mi][0] = __builtin_amdgcn_mfma_f32_16x16x32_f16(AF[mi*2+kk], bf0, acc[mi][0], 0, 0, 0); \
              acc[mi][1] = __builtin_amdgcn_mfma_f32_16x16x32_f16(AF[mi*2+kk], bf1, acc[mi][1], 0, 0, 0); \
          } } }

#define GD_STEP(tcur, AFW, AFR, WBUF, RBUF, PW0, PW1, PZ0, PZ1, DOLDA, DOLQ)   \
    { if (DOLDA) { GD_LDA(AFW, (tcur) + 1) } SCHED0()                          \
      GD_DEQ(WBUF, PW0, PW1, PZ0, PZ1)                                         \
      if (DOLQ) { GD_LD(PW0, PW1, PZ0, PZ1, ((tcur) + 3) * BK) }               \
      GD_COMP(AFR, RBUF)                                                       \
      LGKM_BAR() }

    GD_LD(pwA0, pwA1, pzA0, pzA1, 0)
    GD_LDA(afA, 0)
    GD_DEQ(0, pwA0, pwA1, pzA0, pzA1)
    GD_LD(pwA0, pwA1, pzA0, pzA1, BK)
    GD_LD(pwB0, pwB1, pzB0, pzB1, 2 * BK)
    LGKM_BAR()

    for (int t = 0; t < 108; t += 2) {
        GD_STEP(t,     afB, afA, 1, 0, pwA0, pwA1, pzA0, pzA1, 1, 1)
        GD_STEP(t + 1, afA, afB, 0, 1, pwB0, pwB1, pzB0, pzB1, 1, 1)
    }
    GD_STEP(108, afB, afA, 1, 0, pwA0, pwA1, pzA0, pzA1, 1, 1)
    GD_STEP(109, afA, afB, 0, 1, pwB0, pwB1, pzB0, pzB1, 1, 0)
    GD_STEP(110, afB, afA, 1, 0, pwA0, pwA1, pzA0, pzA1, 1, 0)
    GD_COMP(afB, 1)   // tile 111

    float* pp = part + (size_t)sk * MDIM * HIDDEN;
    const int rb = (lane >> 4) * 4, cb = lane & 15;
#pragma unroll
    for (int mi = 0; mi < 4; ++mi)
#pragma unroll
        for (int ni = 0; ni < 2; ++ni) {
            f32x4 a = acc[mi][ni];
            const int mm = m0 + wm + mi * 16 + rb;
            const int nn = n0 + ni * 16 + cb;
#pragma unroll
            for (int rr = 0; rr < 4; ++rr) pp[(size_t)(mm + rr) * HIDDEN + nn] = a[rr];
        }
#undef GD_LDA
#undef GD_LD
#undef GD_DEQ
#undef GD_COMP
#undef GD_STEP
}

// ---------------- reduce split-K partials ----------------

__global__ void reduce_out(const float* __restrict__ part, float* __restrict__ out) {
    int i = blockIdx.x * blockDim.x + threadIdx.x;
    const int Q = MDIM * HIDDEN / 4;
    float4 a = ((const float4*)part)[i];
    float4 b = ((const float4*)part)[i + Q];
    float4 o;
    o.x = a.x + b.x; o.y = a.y + b.y; o.z = a.z + b.z; o.w = a.w + b.w;
    ((float4*)out)[i] = o;
}

// ---------------- launch ----------------

extern "C" void kernel_launch(void* const* d_in, const int* in_sizes, int n_in,
                              void* d_out, int out_size, void* d_ws, size_t ws_size,
                              hipStream_t stream) {
    (void)in_sizes; (void)n_in; (void)out_size; (void)ws_size;

    const float* x  = (const float*)d_in[0];
    const uint32_t* qw1 = (const uint32_t*)d_in[1];
    const float* s1 = (const float*)d_in[2];
    const float* z1 = (const float*)d_in[3];
    const uint32_t* qw3 = (const uint32_t*)d_in[4];
    const float* s3 = (const float*)d_in[5];
    const float* z3 = (const float*)d_in[6];
    const uint32_t* qw2 = (const uint32_t*)d_in[7];
    const float* s2 = (const float*)d_in[8];
    const float* z2 = (const float*)d_in[9];
    float* out = (float*)d_out;

    // ws: xbp 4.19M | sz1 3.67M | sz3 3.67M | sz2 3.67M | hp(f16) 14.68M | part 16.78M
    char* ws = (char*)d_ws;
    ushort*   xbp  = (ushort*)ws;
    uint32_t* szp1 = (uint32_t*)(ws + (size_t)MDIM * HIDDEN * 2);
    uint32_t* szp3 = szp1 + (size_t)G1 * HIDDEN;
    uint32_t* szp2 = szp3 + (size_t)G1 * HIDDEN;
    ushort*   hp   = (ushort*)(szp2 + (size_t)G2 * FFN);
    float*    part = (float*)((char*)hp + (size_t)MDIM * FFN * 2);

    cvt_xp_kernel<<<(MDIM * HIDDEN / 8) / 256, 256, 0, stream>>>(x, xbp);
    build_sz_kernel<<<(G1 * HIDDEN / 2) / 256, 256, 0, stream>>>(s1, z1, szp1);
    build_sz_kernel<<<(G1 * HIDDEN / 2) / 256, 256, 0, stream>>>(s3, z3, szp3);
    build_sz_kernel<<<(G2 * FFN / 2) / 256, 256, 0, stream>>>(s2, z2, szp2);

    gemm_gateup<<<(FFN / 32) * (MDIM / 256), 256, 0, stream>>>(xbp, qw1, szp1, qw3, szp3, hp);
    gemm_down<<<2 * (MDIM / 256) * (HIDDEN / 32), 256, 0, stream>>>(hp, qw2, szp2, part);
    reduce_out<<<(MDIM * HIDDEN / 4) / 256, 256, 0, stream>>>(part, out);
}